// Round 3
// baseline (3215.445 us; speedup 1.0000x reference)
//
#include <hip/hip_runtime.h>
#include <hip/hip_bf16.h>
#include <cstdint>

#define NT 256
#define N_ATOMS_C 600000
#define BATCH_C 24000

constexpr int K_COUNTS[11] = {10000,130000,170000,160000,100000,15000,5000,2500,2500,2500,2500};
constexpr int K_STARTS[11] = {0,10000,140000,310000,470000,570000,585000,590000,592500,595000,597500};

struct AdjPtrs { const int* p[10]; };

__device__ __forceinline__ float selu_f(float x) {
    const float scale = 1.0507009873554805f;
    const float alpha = 1.6732632423543772f;
    return scale * (x > 0.f ? x : alpha * expm1f(x));
}

// feature-strip size per (FIN, DEG): keeps (1+DEG)*FS live values bounded so
// the worst-case instantiation doesn't inflate the kernel's VGPR allocation.
constexpr int pick_fs(int fin, int deg) {
    if (fin == 75) return deg >= 5 ? 5 : 15;
    if (fin == 15) return deg >= 5 ? 5 : 15;
    if (fin == 20) return deg >= 5 ? 5 : 10;
    if (fin == 27) return deg >= 5 ? 3 : 9;
    return fin;
}

// ---------------------------------------------------------------------------
// Per-degree conv body. DEG is compile-time: adjacency pointers live in
// registers (static indices only), strip loads use immediate offsets.
// No rel[] staging: each neighbor value is FMA'd directly into acc
// (linearity of the matmul). Strip loop is #pragma unroll 1 so live values
// per iteration stay at (1+DEG)*FS + FO.
// ---------------------------------------------------------------------------
template<int FIN, int FO, int DEG, bool FUSE>
__device__ __forceinline__ void conv_body(
    int a, int seg_start,
    const float* __restrict__ x, const float* __restrict__ W,
    const float* __restrict__ bias, const int* __restrict__ adj,
    float* __restrict__ y,
    const int* __restrict__ mem, float* __restrict__ sums,
    unsigned* __restrict__ maxs)
{
    constexpr int FS = pick_fs(FIN, DEG);
    static_assert(FIN % FS == 0, "FS must divide FIN");
    constexpr int NS = FIN / FS;
    constexpr int wi_a = (DEG == 0) ? 20 : 2 * (DEG - 1);
    constexpr int wi_b = (DEG == 0) ? 20 : 2 * DEG - 1;

    const float* wa = W + wi_a * FIN * FO;
    const float* wb = W + wi_b * FIN * FO;

    float acc[FO];
#pragma unroll
    for (int o = 0; o < FO; ++o)
        acc[o] = (DEG > 0) ? (bias[wi_a * FO + o] + bias[wi_b * FO + o])
                           : bias[wi_b * FO + o];

    const int atom = seg_start + a;
    const float* ps = x + (size_t)atom * FIN;
    const float* pn[DEG > 0 ? DEG : 1];
    if constexpr (DEG > 0) {
        const int* ar = adj + (size_t)a * DEG;
#pragma unroll
        for (int k = 0; k < DEG; ++k) pn[k] = x + (size_t)ar[k] * FIN;
    }

#pragma unroll 1
    for (int st = 0; st < NS; ++st) {
        // self strip
        {
            float sv[FS];
#pragma unroll
            for (int f = 0; f < FS; ++f) sv[f] = ps[f];
#pragma unroll
            for (int f = 0; f < FS; ++f)
#pragma unroll
                for (int o = 0; o < FO; ++o)
                    acc[o] = fmaf(sv[f], wb[f * FO + o], acc[o]);
        }
        // neighbor strips, FMA'd directly (no rel accumulation array)
        if constexpr (DEG > 0) {
#pragma unroll
            for (int k = 0; k < DEG; ++k) {
                float tv[FS];
#pragma unroll
                for (int f = 0; f < FS; ++f) tv[f] = pn[k][f];
#pragma unroll
                for (int f = 0; f < FS; ++f)
#pragma unroll
                    for (int o = 0; o < FO; ++o)
                        acc[o] = fmaf(tv[f], wa[f * FO + o], acc[o]);
            }
        }
        // bump pointers
        ps += FS; wb += FS * FO;
        if constexpr (DEG > 0) {
            wa += FS * FO;
#pragma unroll
            for (int k = 0; k < DEG; ++k) pn[k] += FS;
        }
    }

    if constexpr (!FUSE) {
        float* yp = y + (size_t)atom * FO;
#pragma unroll
        for (int o = 0; o < FO; ++o) yp[o] = selu_f(acc[o]);
    } else {
        const int m = mem[atom];
#pragma unroll
        for (int o = 0; o < FO; ++o) {
            const float v = selu_f(acc[o]);
            atomicAdd(&sums[m * FO + o], v);
            const unsigned bits = __float_as_uint(v);
            const unsigned enc = bits ^ ((bits >> 31) ? 0xFFFFFFFFu : 0x80000000u);
            atomicMax(&maxs[m * FO + o], enc);
        }
    }
}

template<int FIN, int FO, bool FUSE>
__global__ __launch_bounds__(256) void conv_kernel(
    const float* __restrict__ x, const float* __restrict__ W,
    const float* __restrict__ bias, AdjPtrs adjp,
    float* __restrict__ y,
    const int* __restrict__ mem, float* __restrict__ sums,
    unsigned* __restrict__ maxs)
{
    // block -> (degree, tile): compile-time table, wave-uniform
    int blk = blockIdx.x;
    int deg = 0, s = 0, cnt = 0;
#pragma unroll
    for (int d = 0; d < 11; ++d) {
        const int nb = (K_COUNTS[d] + NT - 1) / NT;
        if (blk < nb) { deg = d; s = K_STARTS[d]; cnt = K_COUNTS[d]; break; }
        blk -= nb;
    }
    const int a = blk * NT + threadIdx.x;
    if (a >= cnt) return;

#define CASE(D) case D: conv_body<FIN, FO, D, FUSE>(a, s, x, W, bias, \
        (D > 0 ? adjp.p[(D > 0 ? D : 1) - 1] : nullptr), y, mem, sums, maxs); break;
    switch (deg) {
        CASE(0) CASE(1) CASE(2) CASE(3) CASE(4) CASE(5)
        CASE(6) CASE(7) CASE(8) CASE(9) CASE(10)
    }
#undef CASE
}

// ---------------------------------------------------------------------------
__global__ __launch_bounds__(256) void init_kernel(float* __restrict__ sums,
                                                   unsigned* __restrict__ maxs)
{
    const int i = blockIdx.x * NT + threadIdx.x;
    if (i < BATCH_C * 36) { sums[i] = 0.f; maxs[i] = 0x007FFFFFu; } // enc(-inf)
}

// ---------------------------------------------------------------------------
// mol = tanh([sums, decode(maxs)]); logits = mol @ Wd + bd; softmax pairs
// ---------------------------------------------------------------------------
__global__ __launch_bounds__(256) void dense_kernel(
    const float* __restrict__ sums, const unsigned* __restrict__ maxs,
    const float* __restrict__ Wd,   // (72, 24)
    const float* __restrict__ bd,   // (24)
    float* __restrict__ out)        // (BATCH, 12, 2)
{
    __shared__ float sW[72 * 24];
    __shared__ float sb[24];
    __shared__ float sMol[64][72];

    const int tid = threadIdx.x;
    for (int i = tid; i < 72 * 24; i += NT) sW[i] = Wd[i];
    if (tid < 24) sb[tid] = bd[tid];

    const int m0 = blockIdx.x * 64;
    for (int i = tid; i < 64 * 36; i += NT) {
        const int j = i / 36, f = i - j * 36;
        const int m = m0 + j;
        if (m < BATCH_C) {
            sMol[j][f] = tanhf(sums[m * 36 + f]);
            const unsigned enc = maxs[m * 36 + f];
            const unsigned bits = (enc & 0x80000000u) ? (enc ^ 0x80000000u) : ~enc;
            sMol[j][36 + f] = tanhf(__uint_as_float(bits));
        }
    }
    __syncthreads();

    for (int i = tid; i < 64 * 12; i += NT) {
        const int j = i / 12, t = i - j * 12;
        const int m = m0 + j;
        if (m >= BATCH_C) continue;
        float l0 = sb[2 * t], l1 = sb[2 * t + 1];
#pragma unroll
        for (int f = 0; f < 72; ++f) {
            const float v = sMol[j][f];
            l0 += v * sW[f * 24 + 2 * t];
            l1 += v * sW[f * 24 + 2 * t + 1];
        }
        const float mx = fmaxf(l0, l1);
        const float e0 = expf(l0 - mx), e1 = expf(l1 - mx);
        const float inv = 1.f / (e0 + e1);
        out[m * 24 + 2 * t]     = e0 * inv;
        out[m * 24 + 2 * t + 1] = e1 * inv;
    }
}

// ---------------------------------------------------------------------------
extern "C" void kernel_launch(void* const* d_in, const int* in_sizes, int n_in,
                              void* d_out, int out_size, void* d_ws, size_t ws_size,
                              hipStream_t stream)
{
    const float* x0         = (const float*)d_in[0];
    const int*   membership = (const int*)d_in[2];
    AdjPtrs adj;
    for (int d = 0; d < 10; ++d) adj.p[d] = (const int*)d_in[3 + d];
    const float *W1=(const float*)d_in[13], *b1=(const float*)d_in[14];
    const float *W2=(const float*)d_in[15], *b2=(const float*)d_in[16];
    const float *W3=(const float*)d_in[17], *b3=(const float*)d_in[18];
    const float *W4=(const float*)d_in[19], *b4=(const float*)d_in[20];
    const float *Wd=(const float*)d_in[21], *bd=(const float*)d_in[22];

    // workspace: bufA 600000*27, bufB 600000*20, sums 24000*36, maxs 24000*36
    const size_t needA = (size_t)N_ATOMS_C * 27, needB = (size_t)N_ATOMS_C * 20;
    const size_t needBytes = (needA + needB + 2ull * BATCH_C * 36) * 4ull;
    if (ws_size < needBytes) return;

    float* bufA = (float*)d_ws;
    float* bufB = bufA + needA;
    float* sums = bufB + needB;
    unsigned* maxs = (unsigned*)(sums + BATCH_C * 36);

    int nblk = 0;
    for (int d = 0; d < 11; ++d) nblk += (K_COUNTS[d] + NT - 1) / NT;

    init_kernel<<<(BATCH_C * 36 + NT - 1) / NT, NT, 0, stream>>>(sums, maxs);

    conv_kernel<75,15,false><<<nblk, NT, 0, stream>>>(x0,  W1, b1, adj, bufA, nullptr, nullptr, nullptr);
    conv_kernel<15,20,false><<<nblk, NT, 0, stream>>>(bufA, W2, b2, adj, bufB, nullptr, nullptr, nullptr);
    conv_kernel<20,27,false><<<nblk, NT, 0, stream>>>(bufB, W3, b3, adj, bufA, nullptr, nullptr, nullptr);
    conv_kernel<27,36,true ><<<nblk, NT, 0, stream>>>(bufA, W4, b4, adj, nullptr, membership, sums, maxs);

    dense_kernel<<<(BATCH_C + 63) / 64, NT, 0, stream>>>(sums, maxs, Wd, bd, (float*)d_out);
}

// Round 4
// 690.037 us; speedup vs baseline: 4.6598x; 4.6598x over previous
//
#include <hip/hip_runtime.h>
#include <hip/hip_bf16.h>
#include <cstdint>

#define NT 256
#define N_ATOMS_C 600000
#define BATCH_C 24000

constexpr int K_COUNTS[11] = {10000,130000,170000,160000,100000,15000,5000,2500,2500,2500,2500};
constexpr int K_STARTS[11] = {0,10000,140000,310000,470000,570000,585000,590000,592500,595000,597500};

struct AdjPtrs { const int* p[10]; };

__device__ __forceinline__ float selu_f(float x) {
    const float scale = 1.0507009873554805f;
    const float alpha = 1.6732632423543772f;
    return scale * (x > 0.f ? x : alpha * expm1f(x));
}

// ---------------------------------------------------------------------------
// Conv layer: thread = atom, no LDS, no barriers, single code path
// (runtime deg loop; deg is wave-uniform so weight loads scalarize).
// FINP/FOP are padded strides so rows are float4-aligned (pad written as 0).
// FS strips the input features (FIN=75 -> 3x25) to bound live registers.
// ---------------------------------------------------------------------------
template<int FIN, int FINP, int FO, int FOP, int FS>
__global__ __launch_bounds__(256) void conv_kernel(
    const float* __restrict__ x,      // (N_ATOMS, FINP)
    const float* __restrict__ W,      // (21, FIN, FO)
    const float* __restrict__ bias,   // (21, FO)
    AdjPtrs adjp,
    float* __restrict__ y)            // (N_ATOMS, FOP)
{
    // block -> (degree, tile): compile-time table, wave-uniform
    int blk = blockIdx.x;
    int deg = 0, s = 0, cnt = 0;
#pragma unroll
    for (int d = 0; d < 11; ++d) {
        const int nb = (K_COUNTS[d] + NT - 1) / NT;
        if (blk < nb) { deg = d; s = K_STARTS[d]; cnt = K_COUNTS[d]; break; }
        blk -= nb;
    }
    const int a = blk * NT + threadIdx.x;
    if (a >= cnt) return;
    const int atom = s + a;

    const int wi_a = (deg == 0) ? 20 : 2 * (deg - 1);
    const int wi_b = (deg == 0) ? 20 : 2 * deg - 1;
    const float* Wa = W + wi_a * FIN * FO;
    const float* Wb = W + wi_b * FIN * FO;

    float acc[FO];
#pragma unroll
    for (int o = 0; o < FO; ++o)
        acc[o] = bias[wi_b * FO + o] + ((deg > 0) ? bias[wi_a * FO + o] : 0.f);

    const int* myadj = (deg > 0) ? (adjp.p[deg - 1] + (size_t)a * deg) : nullptr;

    constexpr bool VEC = (FINP % 4 == 0) && (FS == FINP);
    constexpr int NS = FINP / FS;

#pragma unroll 1
    for (int st = 0; st < NS; ++st) {
        const int f0 = st * FS;
        float r[FS];
        // ---- self strip ----
        if constexpr (VEC) {
            const float4* p4 = reinterpret_cast<const float4*>(x + (size_t)atom * FINP);
#pragma unroll
            for (int v = 0; v < FS / 4; ++v) {
                const float4 t = p4[v];
                r[4*v] = t.x; r[4*v+1] = t.y; r[4*v+2] = t.z; r[4*v+3] = t.w;
            }
        } else {
            const float* ps = x + (size_t)atom * FINP + f0;
#pragma unroll
            for (int f = 0; f < FS; ++f) r[f] = ps[f];
        }
#pragma unroll
        for (int f = 0; f < FS; ++f) {
            if (f0 + f < FIN) {
#pragma unroll
                for (int o = 0; o < FO; ++o)
                    acc[o] = fmaf(r[f], Wb[(f0 + f) * FO + o], acc[o]);
            }
        }
        // ---- neighbor strips: accumulate rel strip then FMA ----
        if (deg > 0) {
#pragma unroll
            for (int f = 0; f < FS; ++f) r[f] = 0.f;
            for (int k = 0; k < deg; ++k) {
                if constexpr (VEC) {
                    const float4* pk = reinterpret_cast<const float4*>(x + (size_t)myadj[k] * FINP);
#pragma unroll
                    for (int v = 0; v < FS / 4; ++v) {
                        const float4 t = pk[v];
                        r[4*v] += t.x; r[4*v+1] += t.y; r[4*v+2] += t.z; r[4*v+3] += t.w;
                    }
                } else {
                    const float* pk = x + (size_t)myadj[k] * FINP + f0;
#pragma unroll
                    for (int f = 0; f < FS; ++f) r[f] += pk[f];
                }
            }
#pragma unroll
            for (int f = 0; f < FS; ++f) {
                if (f0 + f < FIN) {
#pragma unroll
                    for (int o = 0; o < FO; ++o)
                        acc[o] = fmaf(r[f], Wa[(f0 + f) * FO + o], acc[o]);
                }
            }
        }
    }

    // ---- write (pad -> 0, vectorized when FOP%4==0) ----
    float outv[FOP];
#pragma unroll
    for (int o = 0; o < FOP; ++o) outv[o] = (o < FO) ? selu_f(acc[o]) : 0.f;
    if constexpr (FOP % 4 == 0) {
        float4* yp = reinterpret_cast<float4*>(y + (size_t)atom * FOP);
#pragma unroll
        for (int v = 0; v < FOP / 4; ++v)
            yp[v] = make_float4(outv[4*v], outv[4*v+1], outv[4*v+2], outv[4*v+3]);
    } else {
        float* yp = y + (size_t)atom * FOP;
#pragma unroll
        for (int o = 0; o < FO; ++o) yp[o] = outv[o];
    }
}

// ---------------------------------------------------------------------------
// inverted-index build: count -> scan -> scatter (only int atomics, coalesced)
// ---------------------------------------------------------------------------
__global__ __launch_bounds__(256) void zero_cnt_kernel(int* __restrict__ cnt) {
    const int i = blockIdx.x * NT + threadIdx.x;
    if (i < BATCH_C) cnt[i] = 0;
}

__global__ __launch_bounds__(256) void count_kernel(const int* __restrict__ mem,
                                                    int* __restrict__ cnt) {
    const int i = blockIdx.x * NT + threadIdx.x;
    if (i < N_ATOMS_C) atomicAdd(&cnt[mem[i]], 1);
}

__global__ __launch_bounds__(1024) void scan_kernel(const int* __restrict__ cnt,
                                                    int* __restrict__ base,
                                                    int* __restrict__ cursor) {
    __shared__ int part[1024];
    const int tid = threadIdx.x;
    constexpr int CH = 24;                      // 1024*24 = 24576 >= 24000
    const int i0 = tid * CH;
    int sum = 0;
    for (int j = 0; j < CH; ++j) {
        const int i = i0 + j;
        if (i < BATCH_C) sum += cnt[i];
    }
    part[tid] = sum;
    __syncthreads();
    for (int off = 1; off < 1024; off <<= 1) {
        const int v = (tid >= off) ? part[tid - off] : 0;
        __syncthreads();
        part[tid] += v;
        __syncthreads();
    }
    int run = part[tid] - sum;                  // exclusive prefix
    for (int j = 0; j < CH; ++j) {
        const int i = i0 + j;
        if (i < BATCH_C) { base[i] = run; cursor[i] = run; run += cnt[i]; }
    }
    if (tid == 1023) base[BATCH_C] = part[1023];
}

__global__ __launch_bounds__(256) void scatter_kernel(const int* __restrict__ mem,
                                                      int* __restrict__ cursor,
                                                      int* __restrict__ alist) {
    const int i = blockIdx.x * NT + threadIdx.x;
    if (i < N_ATOMS_C) {
        const int p = atomicAdd(&cursor[mem[i]], 1);
        alist[p] = i;
    }
}

// ---------------------------------------------------------------------------
// one wave per molecule: register sum/max over its atoms, then fused
// tanh -> 72x24 dense -> pairwise softmax. No global atomics.
// ---------------------------------------------------------------------------
__global__ __launch_bounds__(256) void reduce_dense_kernel(
    const float* __restrict__ y4,     // (N_ATOMS, 36)
    const int* __restrict__ base,     // (BATCH+1)
    const int* __restrict__ alist,    // (N_ATOMS)
    const float* __restrict__ Wd,     // (72, 24)
    const float* __restrict__ bd,     // (24)
    float* __restrict__ out)          // (BATCH, 12, 2)
{
    __shared__ float sW[72 * 24];
    __shared__ float sb[24];
    __shared__ float molf[4][72];

    const int tid = threadIdx.x;
    for (int i = tid; i < 72 * 24; i += NT) sW[i] = Wd[i];
    if (tid < 24) sb[tid] = bd[tid];
    __syncthreads();

    const int w = tid >> 6, lane = tid & 63;
    const int mol = blockIdx.x * 4 + w;          // 6000 blocks * 4 = 24000
    const int b0 = base[mol], b1 = base[mol + 1];

    if (lane < 36) {
        float s = 0.f, mx = -INFINITY;
        for (int k = b0; k < b1; ++k) {
            const int atom = alist[k];
            const float v = y4[(size_t)atom * 36 + lane];
            s += v; mx = fmaxf(mx, v);
        }
        molf[w][lane] = tanhf(s);
        molf[w][36 + lane] = tanhf(mx);
    }
    __syncthreads();

    if (lane < 24) {
        float l = sb[lane];
#pragma unroll
        for (int f = 0; f < 72; ++f) l += molf[w][f] * sW[f * 24 + lane];
        const float lp = __shfl_xor(l, 1);
        const float m2 = fmaxf(l, lp);
        const float e = expf(l - m2), ep = expf(lp - m2);
        out[(size_t)mol * 24 + lane] = e / (e + ep);
    }
}

// ---------------------------------------------------------------------------
extern "C" void kernel_launch(void* const* d_in, const int* in_sizes, int n_in,
                              void* d_out, int out_size, void* d_ws, size_t ws_size,
                              hipStream_t stream)
{
    const float* x0         = (const float*)d_in[0];
    const int*   membership = (const int*)d_in[2];
    AdjPtrs adj;
    for (int d = 0; d < 10; ++d) adj.p[d] = (const int*)d_in[3 + d];
    const float *W1=(const float*)d_in[13], *b1=(const float*)d_in[14];
    const float *W2=(const float*)d_in[15], *b2=(const float*)d_in[16];
    const float *W3=(const float*)d_in[17], *b3=(const float*)d_in[18];
    const float *W4=(const float*)d_in[19], *b4=(const float*)d_in[20];
    const float *Wd=(const float*)d_in[21], *bd=(const float*)d_in[22];

    // ws layout (floats): R1 = y1(str16)/y3(str28) alias, R2 = y2(str20)/y4(str36)
    const size_t R1 = (size_t)N_ATOMS_C * 28;
    const size_t R2 = (size_t)N_ATOMS_C * 36;
    const size_t nInts = (size_t)N_ATOMS_C + (BATCH_C + 1) + BATCH_C + BATCH_C;
    const size_t needBytes = (R1 + R2) * 4 + nInts * 4;
    if (ws_size < needBytes) return;

    float* y13 = (float*)d_ws;
    float* y24 = y13 + R1;
    int* alist  = (int*)(y24 + R2);
    int* base   = alist + N_ATOMS_C;
    int* cursor = base + (BATCH_C + 1);
    int* cnt    = cursor + BATCH_C;

    int nblk = 0;
    for (int d = 0; d < 11; ++d) nblk += (K_COUNTS[d] + NT - 1) / NT;
    const int nb_atoms = (N_ATOMS_C + NT - 1) / NT;

    // inverted index (independent of convs)
    zero_cnt_kernel<<<(BATCH_C + NT - 1) / NT, NT, 0, stream>>>(cnt);
    count_kernel<<<nb_atoms, NT, 0, stream>>>(membership, cnt);
    scan_kernel<<<1, 1024, 0, stream>>>(cnt, base, cursor);
    scatter_kernel<<<nb_atoms, NT, 0, stream>>>(membership, cursor, alist);

    // conv chain (FIN, FINP, FO, FOP, FS)
    conv_kernel<75,75,15,16,25><<<nblk, NT, 0, stream>>>(x0,  W1, b1, adj, y13);
    conv_kernel<15,16,20,20,16><<<nblk, NT, 0, stream>>>(y13, W2, b2, adj, y24);
    conv_kernel<20,20,27,28,20><<<nblk, NT, 0, stream>>>(y24, W3, b3, adj, y13);
    conv_kernel<27,28,36,36,28><<<nblk, NT, 0, stream>>>(y13, W4, b4, adj, y24);

    reduce_dense_kernel<<<BATCH_C / 4, NT, 0, stream>>>(y24, base, alist, Wd, bd, (float*)d_out);
}

// Round 6
// 648.693 us; speedup vs baseline: 4.9568x; 1.0637x over previous
//
#include <hip/hip_runtime.h>
#include <hip/hip_fp16.h>
#include <cstdint>

#define NT 256
#define N_ATOMS_C 600000
#define BATCH_C 24000

constexpr int K_COUNTS[11] = {10000,130000,170000,160000,100000,15000,5000,2500,2500,2500,2500};
constexpr int K_STARTS[11] = {0,10000,140000,310000,470000,570000,585000,590000,592500,595000,597500};
// heavy-degree-first dispatch order: long blocks start first, cheap ones fill the tail
constexpr int DORD[11] = {10,9,8,7,6,5,4,3,2,1,0};

struct AdjPtrs { const int* p[10]; };

__device__ __forceinline__ float selu_f(float x) {
    const float scale = 1.0507009873554805f;
    const float alpha = 1.6732632423543772f;
    return scale * (x > 0.f ? x : alpha * expm1f(x));
}

// fp16 helpers: unpack uint -> 2 floats (v_cvt_f32_f16), pack 2 floats -> uint (RNE)
__device__ __forceinline__ float2 up2(unsigned u) {
    const __half2 h = __builtin_bit_cast(__half2, u);
    return __half22float2(h);
}
__device__ __forceinline__ unsigned pack2(float a, float b) {
    const __half2 h = __float22half2_rn(make_float2(a, b));
    return __builtin_bit_cast(unsigned, h);
}

// load/accumulate NLD4*4 fp16 feats from a row (uint2 = 4 feats)
template<int NLD4>
__device__ __forceinline__ void load_row(const uint2* __restrict__ p, float* r) {
#pragma unroll
    for (int v = 0; v < NLD4; ++v) {
        const uint2 t = p[v];
        const float2 a = up2(t.x), b = up2(t.y);
        r[4*v] = a.x; r[4*v+1] = a.y; r[4*v+2] = b.x; r[4*v+3] = b.y;
    }
}
template<int NLD4>
__device__ __forceinline__ void add_row(const uint2* __restrict__ p, float* r) {
#pragma unroll
    for (int v = 0; v < NLD4; ++v) {
        const uint2 t = p[v];
        const float2 a = up2(t.x), b = up2(t.y);
        r[4*v] += a.x; r[4*v+1] += a.y; r[4*v+2] += b.x; r[4*v+3] += b.y;
    }
}
template<int NF, int FO>
__device__ __forceinline__ void fma_strip(const float* r, const float* __restrict__ w,
                                          float* acc) {
#pragma unroll
    for (int f = 0; f < NF; ++f)
#pragma unroll
        for (int o = 0; o < FO; ++o)
            acc[o] = fmaf(r[f], w[f * FO + o], acc[o]);
}

// ---------------------------------------------------------------------------
// Conv layer: thread = atom, fp16 activations (f32 accumulation), no LDS,
// no barriers. Weights f32, wave-uniform -> s_load. OUTF32 for last layer
// (protects segment sum/max from last-layer quantization).
// ---------------------------------------------------------------------------
template<int FIN, int FINP, int FO, int FOP, int FS, bool OUTF32>
__global__ __launch_bounds__(256) void conv_kernel(
    const unsigned short* __restrict__ x,  // (N_ATOMS, FINP) fp16
    const float* __restrict__ W,           // (21, FIN, FO)
    const float* __restrict__ bias,        // (21, FO)
    AdjPtrs adjp,
    void* __restrict__ yv)                 // fp16 (FOP stride) or f32
{
    static_assert(FS % 4 == 0 && FINP % 4 == 0, "");
    constexpr int NSF = FIN / FS;            // full strips
    constexpr int TF  = FIN - NSF * FS;      // tail feats
    constexpr int TLD4 = (TF + 3) / 4;
    static_assert(NSF * FS + TLD4 * 4 <= FINP, "tail reads past row");

    int blk = blockIdx.x;
    int deg = 0, s = 0, cnt = 0;
#pragma unroll
    for (int di = 0; di < 11; ++di) {
        const int d = DORD[di];
        const int nb = (K_COUNTS[d] + NT - 1) / NT;
        if (blk < nb) { deg = d; s = K_STARTS[d]; cnt = K_COUNTS[d]; break; }
        blk -= nb;
    }
    const int a = blk * NT + threadIdx.x;
    if (a >= cnt) return;
    const int atom = s + a;

    const int wi_a = (deg == 0) ? 20 : 2 * (deg - 1);
    const int wi_b = (deg == 0) ? 20 : 2 * deg - 1;
    const float* Wa = W + wi_a * FIN * FO;
    const float* Wb = W + wi_b * FIN * FO;

    float acc[FO];
#pragma unroll
    for (int o = 0; o < FO; ++o)
        acc[o] = bias[wi_b * FO + o] + ((deg > 0) ? bias[wi_a * FO + o] : 0.f);

    const int* myadj = (deg > 0) ? (adjp.p[deg - 1] + (size_t)a * deg) : nullptr;
    const uint2* selfrow = reinterpret_cast<const uint2*>(x + (size_t)atom * FINP);

    // full strips (runtime f0, no feature guards)
#pragma unroll 1
    for (int st = 0; st < NSF; ++st) {
        const int f0 = st * FS;
        float r[FS];
        load_row<FS / 4>(selfrow + (f0 >> 2), r);
        fma_strip<FS, FO>(r, Wb + f0 * FO, acc);
        if (deg > 0) {
#pragma unroll
            for (int f = 0; f < FS; ++f) r[f] = 0.f;
            for (int k = 0; k < deg; ++k)
                add_row<FS / 4>(reinterpret_cast<const uint2*>(
                    x + (size_t)myadj[k] * FINP) + (f0 >> 2), r);
            fma_strip<FS, FO>(r, Wa + f0 * FO, acc);
        }
    }
    // tail strip (compile-time f0)
    if constexpr (TF > 0) {
        constexpr int f0 = NSF * FS;
        float r[TLD4 * 4];
        load_row<TLD4>(selfrow + (f0 >> 2), r);
        fma_strip<TF, FO>(r, Wb + f0 * FO, acc);
        if (deg > 0) {
#pragma unroll
            for (int f = 0; f < TLD4 * 4; ++f) r[f] = 0.f;
            for (int k = 0; k < deg; ++k)
                add_row<TLD4>(reinterpret_cast<const uint2*>(
                    x + (size_t)myadj[k] * FINP) + (f0 >> 2), r);
            fma_strip<TF, FO>(r, Wa + f0 * FO, acc);
        }
    }

    float outv[FOP];
#pragma unroll
    for (int o = 0; o < FOP; ++o) outv[o] = (o < FO) ? selu_f(acc[o]) : 0.f;

    if constexpr (OUTF32) {
        float4* yp = reinterpret_cast<float4*>((float*)yv + (size_t)atom * FOP);
#pragma unroll
        for (int v = 0; v < FOP / 4; ++v)
            yp[v] = make_float4(outv[4*v], outv[4*v+1], outv[4*v+2], outv[4*v+3]);
    } else {
        uint2* yp = reinterpret_cast<uint2*>((unsigned short*)yv + (size_t)atom * FOP);
#pragma unroll
        for (int v = 0; v < FOP / 4; ++v)
            yp[v] = make_uint2(pack2(outv[4*v], outv[4*v+1]),
                               pack2(outv[4*v+2], outv[4*v+3]));
    }
}

// ---------------------------------------------------------------------------
// x0 (f32, stride 75) -> fp16 (stride 76, pad 0). thread = 4 feats (uint2).
// ---------------------------------------------------------------------------
__global__ __launch_bounds__(256) void cast_kernel(const float* __restrict__ x0,
                                                   unsigned short* __restrict__ xh)
{
    const int i = blockIdx.x * NT + threadIdx.x;
    if (i >= N_ATOMS_C * 19) return;
    const int atom = i / 19, v = i - atom * 19;
    const int f0 = v * 4;
    float t[4];
#pragma unroll
    for (int j = 0; j < 4; ++j)
        t[j] = (f0 + j < 75) ? x0[(size_t)atom * 75 + f0 + j] : 0.f;
    reinterpret_cast<uint2*>(xh)[i] = make_uint2(pack2(t[0], t[1]), pack2(t[2], t[3]));
}

// ---------------------------------------------------------------------------
// inverted-index build: count -> scan -> scatter
// ---------------------------------------------------------------------------
__global__ __launch_bounds__(256) void zero_cnt_kernel(int* __restrict__ cnt) {
    const int i = blockIdx.x * NT + threadIdx.x;
    if (i < BATCH_C) cnt[i] = 0;
}
__global__ __launch_bounds__(256) void count_kernel(const int* __restrict__ mem,
                                                    int* __restrict__ cnt) {
    const int i = blockIdx.x * NT + threadIdx.x;
    if (i < N_ATOMS_C) atomicAdd(&cnt[mem[i]], 1);
}
__global__ __launch_bounds__(1024) void scan_kernel(const int* __restrict__ cnt,
                                                    int* __restrict__ base,
                                                    int* __restrict__ cursor) {
    __shared__ int part[1024];
    const int tid = threadIdx.x;
    constexpr int CH = 24;
    const int i0 = tid * CH;
    int sum = 0;
    for (int j = 0; j < CH; ++j) { const int i = i0 + j; if (i < BATCH_C) sum += cnt[i]; }
    part[tid] = sum;
    __syncthreads();
    for (int off = 1; off < 1024; off <<= 1) {
        const int v = (tid >= off) ? part[tid - off] : 0;
        __syncthreads(); part[tid] += v; __syncthreads();
    }
    int run = part[tid] - sum;
    for (int j = 0; j < CH; ++j) {
        const int i = i0 + j;
        if (i < BATCH_C) { base[i] = run; cursor[i] = run; run += cnt[i]; }
    }
    if (tid == 1023) base[BATCH_C] = part[1023];
}
__global__ __launch_bounds__(256) void scatter_kernel(const int* __restrict__ mem,
                                                      int* __restrict__ cursor,
                                                      int* __restrict__ alist) {
    const int i = blockIdx.x * NT + threadIdx.x;
    if (i < N_ATOMS_C) { const int p = atomicAdd(&cursor[mem[i]], 1); alist[p] = i; }
}

// ---------------------------------------------------------------------------
// one wave per molecule: register sum/max, fused tanh -> dense -> softmax
// ---------------------------------------------------------------------------
__global__ __launch_bounds__(256) void reduce_dense_kernel(
    const float* __restrict__ y4,     // (N_ATOMS, 36) f32
    const int* __restrict__ base, const int* __restrict__ alist,
    const float* __restrict__ Wd, const float* __restrict__ bd,
    float* __restrict__ out)
{
    __shared__ float sW[72 * 24];
    __shared__ float sb[24];
    __shared__ float molf[4][72];

    const int tid = threadIdx.x;
    for (int i = tid; i < 72 * 24; i += NT) sW[i] = Wd[i];
    if (tid < 24) sb[tid] = bd[tid];
    __syncthreads();

    const int w = tid >> 6, lane = tid & 63;
    const int mol = blockIdx.x * 4 + w;
    const int b0 = base[mol], b1 = base[mol + 1];

    if (lane < 36) {
        float s = 0.f, mx = -INFINITY;
        for (int k = b0; k < b1; ++k) {
            const int atom = alist[k];
            const float v = y4[(size_t)atom * 36 + lane];
            s += v; mx = fmaxf(mx, v);
        }
        molf[w][lane] = tanhf(s);
        molf[w][36 + lane] = tanhf(mx);
    }
    __syncthreads();

    if (lane < 24) {
        float l = sb[lane];
#pragma unroll
        for (int f = 0; f < 72; ++f) l += molf[w][f] * sW[f * 24 + lane];
        const float lp = __shfl_xor(l, 1);
        const float m2 = fmaxf(l, lp);
        const float e = expf(l - m2), ep = expf(lp - m2);
        out[(size_t)mol * 24 + lane] = e / (e + ep);
    }
}

// ---------------------------------------------------------------------------
extern "C" void kernel_launch(void* const* d_in, const int* in_sizes, int n_in,
                              void* d_out, int out_size, void* d_ws, size_t ws_size,
                              hipStream_t stream)
{
    const float* x0         = (const float*)d_in[0];
    const int*   membership = (const int*)d_in[2];
    AdjPtrs adj;
    for (int d = 0; d < 10; ++d) adj.p[d] = (const int*)d_in[3 + d];
    const float *W1=(const float*)d_in[13], *b1=(const float*)d_in[14];
    const float *W2=(const float*)d_in[15], *b2=(const float*)d_in[16];
    const float *W3=(const float*)d_in[17], *b3=(const float*)d_in[18];
    const float *W4=(const float*)d_in[19], *b4=(const float*)d_in[20];
    const float *Wd=(const float*)d_in[21], *bd=(const float*)d_in[22];

    // ws layout:
    //  region A: xh (600000x76 fp16 = 91.2 MB), later reused for y4 (f32, 86.4 MB)
    //  region B: y1 (stride16) / y3 (stride28) fp16 = 33.6 MB
    //  region C: y2 (stride20) fp16 = 24 MB
    //  ints: alist, base, cursor, cnt
    const size_t szA = (size_t)N_ATOMS_C * 76 * 2;             // bytes
    const size_t szB = (size_t)N_ATOMS_C * 28 * 2;
    const size_t szC = (size_t)N_ATOMS_C * 20 * 2;
    const size_t nInts = (size_t)N_ATOMS_C + (BATCH_C + 1) + BATCH_C + BATCH_C;
    if (ws_size < szA + szB + szC + nInts * 4) return;

    unsigned short* xh  = (unsigned short*)d_ws;
    float*          y4  = (float*)d_ws;                        // alias A (xh dead after L1)
    unsigned short* y13 = (unsigned short*)((char*)d_ws + szA);
    unsigned short* y2  = (unsigned short*)((char*)d_ws + szA + szB);
    int* alist  = (int*)((char*)d_ws + szA + szB + szC);
    int* base   = alist + N_ATOMS_C;
    int* cursor = base + (BATCH_C + 1);
    int* cnt    = cursor + BATCH_C;

    int nblk = 0;
    for (int d = 0; d < 11; ++d) nblk += (K_COUNTS[d] + NT - 1) / NT;
    const int nb_atoms = (N_ATOMS_C + NT - 1) / NT;

    cast_kernel<<<(N_ATOMS_C * 19 + NT - 1) / NT, NT, 0, stream>>>(x0, xh);

    zero_cnt_kernel<<<(BATCH_C + NT - 1) / NT, NT, 0, stream>>>(cnt);
    count_kernel<<<nb_atoms, NT, 0, stream>>>(membership, cnt);
    scan_kernel<<<1, 1024, 0, stream>>>(cnt, base, cursor);
    scatter_kernel<<<nb_atoms, NT, 0, stream>>>(membership, cursor, alist);

    // conv chain <FIN, FINP, FO, FOP, FS, OUTF32>
    conv_kernel<75,76,15,16,20,false><<<nblk, NT, 0, stream>>>(xh,  W1, b1, adj, y13);
    conv_kernel<15,16,20,20,16,false><<<nblk, NT, 0, stream>>>(y13, W2, b2, adj, y2);
    conv_kernel<20,20,27,28,20,false><<<nblk, NT, 0, stream>>>(y2,  W3, b3, adj, y13);
    conv_kernel<27,28,36,36,28,true ><<<nblk, NT, 0, stream>>>(y13, W4, b4, adj, y4);

    reduce_dense_kernel<<<BATCH_C / 4, NT, 0, stream>>>(y4, base, alist, Wd, bd, (float*)d_out);
}

// Round 7
// 619.069 us; speedup vs baseline: 5.1940x; 1.0479x over previous
//
#include <hip/hip_runtime.h>
#include <hip/hip_fp16.h>
#include <cstdint>

#define NT 256
#define N_ATOMS_C 600000
#define BATCH_C 24000

constexpr int K_COUNTS[11] = {10000,130000,170000,160000,100000,15000,5000,2500,2500,2500,2500};
constexpr int K_STARTS[11] = {0,10000,140000,310000,470000,570000,585000,590000,592500,595000,597500};
// heavy-degree-first dispatch order: long blocks start first, cheap ones fill the tail
constexpr int DORD[11] = {10,9,8,7,6,5,4,3,2,1,0};

struct AdjPtrs { const int* p[10]; };

__device__ __forceinline__ float selu_f(float x) {
    const float scale = 1.0507009873554805f;
    const float alpha = 1.6732632423543772f;
    return scale * (x > 0.f ? x : alpha * expm1f(x));
}

// fp16 helpers: unpack uint -> 2 floats (v_cvt_f32_f16), pack 2 floats -> uint (RNE)
__device__ __forceinline__ float2 up2(unsigned u) {
    const __half2 h = __builtin_bit_cast(__half2, u);
    return __half22float2(h);
}
__device__ __forceinline__ unsigned pack2(float a, float b) {
    const __half2 h = __float22half2_rn(make_float2(a, b));
    return __builtin_bit_cast(unsigned, h);
}

// load/accumulate NLD4*4 fp16 feats from a row (uint2 = 4 feats)
template<int NLD4>
__device__ __forceinline__ void load_row(const uint2* __restrict__ p, float* r) {
#pragma unroll
    for (int v = 0; v < NLD4; ++v) {
        const uint2 t = p[v];
        const float2 a = up2(t.x), b = up2(t.y);
        r[4*v] = a.x; r[4*v+1] = a.y; r[4*v+2] = b.x; r[4*v+3] = b.y;
    }
}
template<int NLD4>
__device__ __forceinline__ void add_row(const uint2* __restrict__ p, float* r) {
#pragma unroll
    for (int v = 0; v < NLD4; ++v) {
        const uint2 t = p[v];
        const float2 a = up2(t.x), b = up2(t.y);
        r[4*v] += a.x; r[4*v+1] += a.y; r[4*v+2] += b.x; r[4*v+3] += b.y;
    }
}
template<int NF, int FO>
__device__ __forceinline__ void fma_strip(const float* r, const float* __restrict__ w,
                                          float* acc) {
#pragma unroll
    for (int f = 0; f < NF; ++f)
#pragma unroll
        for (int o = 0; o < FO; ++o)
            acc[o] = fmaf(r[f], w[f * FO + o], acc[o]);
}

// ---------------------------------------------------------------------------
// Conv layer: thread = atom, fp16 activations (f32 accumulation), no LDS,
// no barriers. Full-row register loads (FS >= FINP) maximize per-wave
// outstanding loads on the random-gather path. Weights f32, wave-uniform
// -> s_load. OUTF32 selects f32 output (unused now; kept for flexibility).
// ---------------------------------------------------------------------------
template<int FIN, int FINP, int FO, int FOP, int FS, bool OUTF32>
__global__ __launch_bounds__(256) void conv_kernel(
    const unsigned short* __restrict__ x,  // (N_ATOMS, FINP) fp16
    const float* __restrict__ W,           // (21, FIN, FO)
    const float* __restrict__ bias,        // (21, FO)
    AdjPtrs adjp,
    void* __restrict__ yv)                 // fp16 (FOP stride) or f32
{
    static_assert(FS % 4 == 0 && FINP % 4 == 0, "");
    constexpr int NSF = FIN / FS;            // full strips
    constexpr int TF  = FIN - NSF * FS;      // tail feats
    constexpr int TLD4 = (TF + 3) / 4;
    static_assert(NSF * FS + TLD4 * 4 <= FINP, "tail reads past row");

    int blk = blockIdx.x;
    int deg = 0, s = 0, cnt = 0;
#pragma unroll
    for (int di = 0; di < 11; ++di) {
        const int d = DORD[di];
        const int nb = (K_COUNTS[d] + NT - 1) / NT;
        if (blk < nb) { deg = d; s = K_STARTS[d]; cnt = K_COUNTS[d]; break; }
        blk -= nb;
    }
    const int a = blk * NT + threadIdx.x;
    if (a >= cnt) return;
    const int atom = s + a;

    const int wi_a = (deg == 0) ? 20 : 2 * (deg - 1);
    const int wi_b = (deg == 0) ? 20 : 2 * deg - 1;
    const float* Wa = W + wi_a * FIN * FO;
    const float* Wb = W + wi_b * FIN * FO;

    float acc[FO];
#pragma unroll
    for (int o = 0; o < FO; ++o)
        acc[o] = bias[wi_b * FO + o] + ((deg > 0) ? bias[wi_a * FO + o] : 0.f);

    const int* myadj = (deg > 0) ? (adjp.p[deg - 1] + (size_t)a * deg) : nullptr;
    const uint2* selfrow = reinterpret_cast<const uint2*>(x + (size_t)atom * FINP);

    // full strips (runtime f0, no feature guards)
#pragma unroll 1
    for (int st = 0; st < NSF; ++st) {
        const int f0 = st * FS;
        float r[FS];
        load_row<FS / 4>(selfrow + (f0 >> 2), r);
        fma_strip<FS, FO>(r, Wb + f0 * FO, acc);
        if (deg > 0) {
#pragma unroll
            for (int f = 0; f < FS; ++f) r[f] = 0.f;
            for (int k = 0; k < deg; ++k)
                add_row<FS / 4>(reinterpret_cast<const uint2*>(
                    x + (size_t)myadj[k] * FINP) + (f0 >> 2), r);
            fma_strip<FS, FO>(r, Wa + f0 * FO, acc);
        }
    }
    // tail strip (compile-time f0)
    if constexpr (TF > 0) {
        constexpr int f0 = NSF * FS;
        float r[TLD4 * 4];
        load_row<TLD4>(selfrow + (f0 >> 2), r);
        fma_strip<TF, FO>(r, Wb + f0 * FO, acc);
        if (deg > 0) {
#pragma unroll
            for (int f = 0; f < TLD4 * 4; ++f) r[f] = 0.f;
            for (int k = 0; k < deg; ++k)
                add_row<TLD4>(reinterpret_cast<const uint2*>(
                    x + (size_t)myadj[k] * FINP) + (f0 >> 2), r);
            fma_strip<TF, FO>(r, Wa + f0 * FO, acc);
        }
    }

    float outv[FOP];
#pragma unroll
    for (int o = 0; o < FOP; ++o) outv[o] = (o < FO) ? selu_f(acc[o]) : 0.f;

    if constexpr (OUTF32) {
        float4* yp = reinterpret_cast<float4*>((float*)yv + (size_t)atom * FOP);
#pragma unroll
        for (int v = 0; v < FOP / 4; ++v)
            yp[v] = make_float4(outv[4*v], outv[4*v+1], outv[4*v+2], outv[4*v+3]);
    } else {
        uint2* yp = reinterpret_cast<uint2*>((unsigned short*)yv + (size_t)atom * FOP);
#pragma unroll
        for (int v = 0; v < FOP / 4; ++v)
            yp[v] = make_uint2(pack2(outv[4*v], outv[4*v+1]),
                               pack2(outv[4*v+2], outv[4*v+3]));
    }
}

// ---------------------------------------------------------------------------
// x0 (f32, stride 75) -> fp16 (stride 76, pad 0). thread = 4 feats (uint2).
// ---------------------------------------------------------------------------
__global__ __launch_bounds__(256) void cast_kernel(const float* __restrict__ x0,
                                                   unsigned short* __restrict__ xh)
{
    const int i = blockIdx.x * NT + threadIdx.x;
    if (i >= N_ATOMS_C * 19) return;
    const int atom = i / 19, v = i - atom * 19;
    const int f0 = v * 4;
    float t[4];
#pragma unroll
    for (int j = 0; j < 4; ++j)
        t[j] = (f0 + j < 75) ? x0[(size_t)atom * 75 + f0 + j] : 0.f;
    reinterpret_cast<uint2*>(xh)[i] = make_uint2(pack2(t[0], t[1]), pack2(t[2], t[3]));
}

// ---------------------------------------------------------------------------
// inverted-index build: count -> scan -> scatter
// ---------------------------------------------------------------------------
__global__ __launch_bounds__(256) void zero_cnt_kernel(int* __restrict__ cnt) {
    const int i = blockIdx.x * NT + threadIdx.x;
    if (i < BATCH_C) cnt[i] = 0;
}
__global__ __launch_bounds__(256) void count_kernel(const int* __restrict__ mem,
                                                    int* __restrict__ cnt) {
    const int i = blockIdx.x * NT + threadIdx.x;
    if (i < N_ATOMS_C) atomicAdd(&cnt[mem[i]], 1);
}
__global__ __launch_bounds__(1024) void scan_kernel(const int* __restrict__ cnt,
                                                    int* __restrict__ base,
                                                    int* __restrict__ cursor) {
    __shared__ int part[1024];
    const int tid = threadIdx.x;
    constexpr int CH = 24;
    const int i0 = tid * CH;
    int sum = 0;
    for (int j = 0; j < CH; ++j) { const int i = i0 + j; if (i < BATCH_C) sum += cnt[i]; }
    part[tid] = sum;
    __syncthreads();
    for (int off = 1; off < 1024; off <<= 1) {
        const int v = (tid >= off) ? part[tid - off] : 0;
        __syncthreads(); part[tid] += v; __syncthreads();
    }
    int run = part[tid] - sum;
    for (int j = 0; j < CH; ++j) {
        const int i = i0 + j;
        if (i < BATCH_C) { base[i] = run; cursor[i] = run; run += cnt[i]; }
    }
    if (tid == 1023) base[BATCH_C] = part[1023];
}
__global__ __launch_bounds__(256) void scatter_kernel(const int* __restrict__ mem,
                                                      int* __restrict__ cursor,
                                                      int* __restrict__ alist) {
    const int i = blockIdx.x * NT + threadIdx.x;
    if (i < N_ATOMS_C) { const int p = atomicAdd(&cursor[mem[i]], 1); alist[p] = i; }
}

// ---------------------------------------------------------------------------
// one wave per molecule: register sum/max over fp16 y4 rows, fused
// tanh -> 72x24 dense -> pairwise softmax
// ---------------------------------------------------------------------------
__global__ __launch_bounds__(256) void reduce_dense_kernel(
    const unsigned short* __restrict__ y4,  // (N_ATOMS, 36) fp16
    const int* __restrict__ base, const int* __restrict__ alist,
    const float* __restrict__ Wd, const float* __restrict__ bd,
    float* __restrict__ out)
{
    __shared__ float sW[72 * 24];
    __shared__ float sb[24];
    __shared__ float molf[4][72];

    const int tid = threadIdx.x;
    for (int i = tid; i < 72 * 24; i += NT) sW[i] = Wd[i];
    if (tid < 24) sb[tid] = bd[tid];
    __syncthreads();

    const int w = tid >> 6, lane = tid & 63;
    const int mol = blockIdx.x * 4 + w;
    const int b0 = base[mol], b1 = base[mol + 1];

    if (lane < 36) {
        float s = 0.f, mx = -INFINITY;
        for (int k = b0; k < b1; ++k) {
            const int atom = alist[k];
            const float v = __half2float(__builtin_bit_cast(__half,
                                y4[(size_t)atom * 36 + lane]));
            s += v; mx = fmaxf(mx, v);
        }
        molf[w][lane] = tanhf(s);
        molf[w][36 + lane] = tanhf(mx);
    }
    __syncthreads();

    if (lane < 24) {
        float l = sb[lane];
#pragma unroll
        for (int f = 0; f < 72; ++f) l += molf[w][f] * sW[f * 24 + lane];
        const float lp = __shfl_xor(l, 1);
        const float m2 = fmaxf(l, lp);
        const float e = expf(l - m2), ep = expf(lp - m2);
        out[(size_t)mol * 24 + lane] = e / (e + ep);
    }
}

// ---------------------------------------------------------------------------
extern "C" void kernel_launch(void* const* d_in, const int* in_sizes, int n_in,
                              void* d_out, int out_size, void* d_ws, size_t ws_size,
                              hipStream_t stream)
{
    const float* x0         = (const float*)d_in[0];
    const int*   membership = (const int*)d_in[2];
    AdjPtrs adj;
    for (int d = 0; d < 10; ++d) adj.p[d] = (const int*)d_in[3 + d];
    const float *W1=(const float*)d_in[13], *b1=(const float*)d_in[14];
    const float *W2=(const float*)d_in[15], *b2=(const float*)d_in[16];
    const float *W3=(const float*)d_in[17], *b3=(const float*)d_in[18];
    const float *W4=(const float*)d_in[19], *b4=(const float*)d_in[20];
    const float *Wd=(const float*)d_in[21], *bd=(const float*)d_in[22];

    // ws layout:
    //  region A: xh (600000x76 fp16 = 91.2 MB), later reused for y4 (fp16, 43.2 MB)
    //  region B: y1 (stride16) / y3 (stride28) fp16 = 33.6 MB
    //  region C: y2 (stride20) fp16 = 24 MB
    //  ints: alist, base, cursor, cnt
    const size_t szA = (size_t)N_ATOMS_C * 76 * 2;             // bytes
    const size_t szB = (size_t)N_ATOMS_C * 28 * 2;
    const size_t szC = (size_t)N_ATOMS_C * 20 * 2;
    const size_t nInts = (size_t)N_ATOMS_C + (BATCH_C + 1) + BATCH_C + BATCH_C;
    if (ws_size < szA + szB + szC + nInts * 4) return;

    unsigned short* xh  = (unsigned short*)d_ws;
    unsigned short* y4  = (unsigned short*)d_ws;               // alias A (xh dead after L1)
    unsigned short* y13 = (unsigned short*)((char*)d_ws + szA);
    unsigned short* y2  = (unsigned short*)((char*)d_ws + szA + szB);
    int* alist  = (int*)((char*)d_ws + szA + szB + szC);
    int* base   = alist + N_ATOMS_C;
    int* cursor = base + (BATCH_C + 1);
    int* cnt    = cursor + BATCH_C;

    int nblk = 0;
    for (int d = 0; d < 11; ++d) nblk += (K_COUNTS[d] + NT - 1) / NT;
    const int nb_atoms = (N_ATOMS_C + NT - 1) / NT;

    cast_kernel<<<(N_ATOMS_C * 19 + NT - 1) / NT, NT, 0, stream>>>(x0, xh);

    zero_cnt_kernel<<<(BATCH_C + NT - 1) / NT, NT, 0, stream>>>(cnt);
    count_kernel<<<nb_atoms, NT, 0, stream>>>(membership, cnt);
    scan_kernel<<<1, 1024, 0, stream>>>(cnt, base, cursor);
    scatter_kernel<<<nb_atoms, NT, 0, stream>>>(membership, cursor, alist);

    // conv chain <FIN, FINP, FO, FOP, FS, OUTF32> — FS >= FINP => full-row loads
    conv_kernel<75,76,15,16,76,false><<<nblk, NT, 0, stream>>>(xh,  W1, b1, adj, y13);
    conv_kernel<15,16,20,20,16,false><<<nblk, NT, 0, stream>>>(y13, W2, b2, adj, y2);
    conv_kernel<20,20,27,28,20,false><<<nblk, NT, 0, stream>>>(y2,  W3, b3, adj, y13);
    conv_kernel<27,28,36,36,28,false><<<nblk, NT, 0, stream>>>(y13, W4, b4, adj, y4);

    reduce_dense_kernel<<<BATCH_C / 4, NT, 0, stream>>>(y4, base, alist, Wd, bd, (float*)d_out);
}